// Round 2
// baseline (790.005 us; speedup 1.0000x reference)
//
#include <hip/hip_runtime.h>
#include <math.h>

// CRF forward partition scan. B=512, S=1024, T=48.
// One 64-lane wave per batch element (512 waves over 256 CUs, ~2/CU).
// Lane j owns tag j (lanes 48..63 clamped). Per-lane VGPRs hold trans
// column T[:,j] and exp(T[:,j]) for all 1024 steps.
// __launch_bounds__(64, 1): min 1 wave/EU -> full 512-VGPR budget.
// R1 post-mortem: without it the compiler capped at 64 VGPRs and spilled
// Tc/Ec to scratch, adding ~1400 cyc of scratch reloads per step.

constexpr int kB = 512;
constexpr int kS = 1024;
constexpr int kT = 48;

__global__ __launch_bounds__(64, 1) void crf_fwd(
    const float* __restrict__ feats,   // [B, S, T] fp32
    const int*   __restrict__ mask,    // [B, S] int32 (bool)
    const float* __restrict__ trans,   // [T, T] fp32
    float*       __restrict__ out)     // [1 + B]; we write out[1+b]
{
    const int b    = blockIdx.x;
    const int lane = threadIdx.x;
    const int j    = (lane < kT) ? lane : (kT - 1);  // clamp idle lanes

    __shared__ alignas(16) float p_sh[64];   // part_i
    __shared__ alignas(16) float ea_sh[64];  // exp(part_i - e_i - M_i)

    // Column j of transition and its exp, resident in VGPRs for all steps.
    float Tc[kT];
    float Ec[kT];
#pragma unroll
    for (int i = 0; i < kT; ++i) {
        Tc[i] = trans[i * kT + j];
        Ec[i] = __expf(Tc[i]);
    }

    const float* fb = feats + (size_t)b * kS * kT + j;  // lane-offset base
    const int*   mb = mask  + (size_t)b * kS;

    // part0 = emit[0] + transition[T-2, :]
    float part = fb[0] + Tc[kT - 2];
    p_sh[lane] = part;
    __syncthreads();

    // Depth-4 register-rotated prefetch of (emission, mask): covers ~4 steps
    // of latency so the HBM/L2 load never lands on the critical path, even
    // right after a burst of masked (cheap) iterations.
    float e0 = fb[(size_t)1 * kT], e1 = fb[(size_t)2 * kT],
          e2 = fb[(size_t)3 * kT], e3 = fb[(size_t)4 * kT];
    int   m0 = mb[1], m1 = mb[2], m2 = mb[3], m3 = mb[4];

    for (int t = 1; t < kS; ++t) {
        const float e  = e0;
        const int   mk = m0;
        e0 = e1; e1 = e2; e2 = e3;
        m0 = m1; m1 = m2; m2 = m3;
        const int tn = (t + 4 < kS) ? (t + 4) : (kS - 1);
        e3 = fb[(size_t)tn * kT];
        m3 = mb[tn];

        if (mk) {  // wave-uniform branch: skip masked-out steps entirely
            const float pe = part - e;  // off critical path (before M known)

            // pass 1: M_j = max_i (T[i,j] + part_i), broadcast LDS reads.
            // 8 accumulators -> dep chain depth 6 (+3 combine levels).
            const float4* p4 = (const float4*)p_sh;
            float a0 = -INFINITY, a1 = -INFINITY, a2 = -INFINITY, a3 = -INFINITY;
            float a4 = -INFINITY, a5 = -INFINITY, a6 = -INFINITY, a7 = -INFINITY;
#pragma unroll
            for (int i = 0; i < kT; i += 8) {
                const float4 pA = p4[(i >> 2) + 0];
                const float4 pB = p4[(i >> 2) + 1];
                a0 = fmaxf(a0, Tc[i + 0] + pA.x);
                a1 = fmaxf(a1, Tc[i + 1] + pA.y);
                a2 = fmaxf(a2, Tc[i + 2] + pA.z);
                a3 = fmaxf(a3, Tc[i + 3] + pA.w);
                a4 = fmaxf(a4, Tc[i + 4] + pB.x);
                a5 = fmaxf(a5, Tc[i + 5] + pB.y);
                a6 = fmaxf(a6, Tc[i + 6] + pB.z);
                a7 = fmaxf(a7, Tc[i + 7] + pB.w);
            }
            const float M = fmaxf(fmaxf(fmaxf(a0, a4), fmaxf(a1, a5)),
                                  fmaxf(fmaxf(a2, a6), fmaxf(a3, a7)));

            // lane i publishes exp(part_i - e_i - M_i)
            const float ea = __expf(pe - M);
            ea_sh[lane] = ea;
            __syncthreads();  // B1 (elided to waitcnt: single-wave block)

            // pass 2: S_j = sum_i exp(T[i,j]) * ea_i  (FMA dot product)
            const float4* q4 = (const float4*)ea_sh;
            float s0 = 0.f, s1 = 0.f, s2 = 0.f, s3 = 0.f;
            float s4 = 0.f, s5 = 0.f, s6 = 0.f, s7 = 0.f;
#pragma unroll
            for (int i = 0; i < kT; i += 8) {
                const float4 qA = q4[(i >> 2) + 0];
                const float4 qB = q4[(i >> 2) + 1];
                s0 = fmaf(Ec[i + 0], qA.x, s0);
                s1 = fmaf(Ec[i + 1], qA.y, s1);
                s2 = fmaf(Ec[i + 2], qA.z, s2);
                s3 = fmaf(Ec[i + 3], qA.w, s3);
                s4 = fmaf(Ec[i + 4], qB.x, s4);
                s5 = fmaf(Ec[i + 5], qB.y, s5);
                s6 = fmaf(Ec[i + 6], qB.z, s6);
                s7 = fmaf(Ec[i + 7], qB.w, s7);
            }
            const float Ssum = ((s0 + s4) + (s1 + s5)) + ((s2 + s6) + (s3 + s7));

            // val_j = 2*e_j + M_j + log(S_j); mask true here so part <- val
            part = 2.0f * e + M + __logf(Ssum);
            p_sh[lane] = part;
            __syncthreads();  // B2: part visible for next step's pass 1
        }
    }

    // Final transition-only step; only end_value[:, T-1] is stored, but all
    // M_i are required, so run both passes.
    {
        const float4* p4 = (const float4*)p_sh;
        float a0 = -INFINITY, a1 = -INFINITY, a2 = -INFINITY, a3 = -INFINITY;
#pragma unroll
        for (int i = 0; i < kT; i += 4) {
            const float4 p = p4[i >> 2];
            a0 = fmaxf(a0, Tc[i + 0] + p.x);
            a1 = fmaxf(a1, Tc[i + 1] + p.y);
            a2 = fmaxf(a2, Tc[i + 2] + p.z);
            a3 = fmaxf(a3, Tc[i + 3] + p.w);
        }
        const float M = fmaxf(fmaxf(a0, a1), fmaxf(a2, a3));
        const float ea = __expf(part - M);   // no emission term in final step
        ea_sh[lane] = ea;
        __syncthreads();

        const float4* q4 = (const float4*)ea_sh;
        float s0 = 0.f, s1 = 0.f, s2 = 0.f, s3 = 0.f;
#pragma unroll
        for (int i = 0; i < kT; i += 4) {
            const float4 q = q4[i >> 2];
            s0 = fmaf(Ec[i + 0], q.x, s0);
            s1 = fmaf(Ec[i + 1], q.y, s1);
            s2 = fmaf(Ec[i + 2], q.z, s2);
            s3 = fmaf(Ec[i + 3], q.w, s3);
        }
        const float Ssum = (s0 + s1) + (s2 + s3);
        const float val = M + __logf(Ssum);
        if (lane == kT - 1) out[1 + b] = val;  // score[b] = end_value[b, -1]
    }
}

// out[0] = sum(score). Single wave; no barriers needed.
__global__ __launch_bounds__(64) void sum_scores(
    const float* __restrict__ sc, float* __restrict__ out)
{
    float s = 0.f;
    for (int i = (int)threadIdx.x; i < kB; i += 64) s += sc[i];
#pragma unroll
    for (int off = 32; off > 0; off >>= 1) s += __shfl_down(s, off);
    if (threadIdx.x == 0) out[0] = s;
}

extern "C" void kernel_launch(void* const* d_in, const int* in_sizes, int n_in,
                              void* d_out, int out_size, void* d_ws, size_t ws_size,
                              hipStream_t stream) {
    const float* feats = (const float*)d_in[0];
    const int*   mask  = (const int*)d_in[1];
    const float* trans = (const float*)d_in[2];
    float*       out   = (float*)d_out;

    crf_fwd<<<dim3(kB), dim3(64), 0, stream>>>(feats, mask, trans, out);
    sum_scores<<<dim3(1), dim3(64), 0, stream>>>(out + 1, out);
}

// Round 3
// 630.741 us; speedup vs baseline: 1.2525x; 1.2525x over previous
//
#include <hip/hip_runtime.h>
#include <math.h>
#include <utility>

// CRF forward partition scan. B=512, S=1024, T=48.
// One 64-lane wave per batch element. Lane j owns tag j (lanes 48..63 clamp).
//
// R2 post-mortem: `float Tc[48]` indexed by a (pragma-unrolled) loop variable
// never got SROA-promoted -> scratch-resident -> ~96 scratch loads/step
// (VGPR_Count=80 proved it; 687 us). Fix: compile-time template unrolling so
// every array index is a literal constant in the frontend IR. Target:
// Tc/Ec resident in VGPRs (expect VGPR_Count ~140-190).

constexpr int kB = 512;
constexpr int kS = 1024;
constexpr int kT = 48;

template <typename F, int... Is>
__device__ __forceinline__ void unroll_impl(F&& f, std::integer_sequence<int, Is...>) {
    (f(std::integral_constant<int, Is>{}), ...);
}
template <int N, typename F>
__device__ __forceinline__ void unroll(F&& f) {
    unroll_impl(static_cast<F&&>(f), std::make_integer_sequence<int, N>{});
}

// Component extract with compile-time index — no address-taking (SROA-safe).
template <int K>
__device__ __forceinline__ float getc(float4 v) {
    if constexpr (K == 0) return v.x;
    else if constexpr (K == 1) return v.y;
    else if constexpr (K == 2) return v.z;
    else return v.w;
}

__global__ __launch_bounds__(64, 1) void crf_fwd(
    const float* __restrict__ feats,   // [B, S, T] fp32
    const int*   __restrict__ mask,    // [B, S] int32 (bool)
    const float* __restrict__ trans,   // [T, T] fp32
    float*       __restrict__ out)     // [1 + B]; we write out[1+b]
{
    const int b    = blockIdx.x;
    const int lane = threadIdx.x;
    const int j    = (lane < kT) ? lane : (kT - 1);  // clamp idle lanes

    __shared__ alignas(16) float p_sh[64];   // part_i
    __shared__ alignas(16) float ea_sh[64];  // exp(part_i - e_i - M_i)
    const float4* p4 = (const float4*)p_sh;
    const float4* q4 = (const float4*)ea_sh;

    // Column j of transition and its exp — compile-time-indexed so SROA
    // promotes both arrays to 96 VGPRs, resident for all 1024 steps.
    float Tc[kT];
    float Ec[kT];
    unroll<kT>([&](auto I) {
        constexpr int i = decltype(I)::value;
        Tc[i] = trans[i * kT + j];
        Ec[i] = __expf(Tc[i]);
    });

    const float* fb = feats + (size_t)b * kS * kT + j;  // lane-offset base
    const int*   mb = mask  + (size_t)b * kS;

    // part0 = emit[0] + transition[T-2, :]
    float part = fb[0] + Tc[kT - 2];
    p_sh[lane] = part;
    __syncthreads();

    // Depth-4 register-rotated prefetch of (emission, mask).
    float e0 = fb[(size_t)1 * kT], e1 = fb[(size_t)2 * kT],
          e2 = fb[(size_t)3 * kT], e3 = fb[(size_t)4 * kT];
    int   m0 = mb[1], m1 = mb[2], m2 = mb[3], m3 = mb[4];

    for (int t = 1; t < kS; ++t) {
        const float e  = e0;
        const int   mk = m0;
        e0 = e1; e1 = e2; e2 = e3;
        m0 = m1; m1 = m2; m2 = m3;
        const int tn = (t + 4 < kS) ? (t + 4) : (kS - 1);
        e3 = fb[(size_t)tn * kT];
        m3 = mb[tn];

        if (mk) {  // wave-uniform branch: skip masked-out steps entirely
            const float pe = part - e;  // off the M-dependent critical path

            // pass 1: M_j = max_i (T[i,j] + part_i).
            // 12 broadcast b128 LDS reads into named float4s (SROA-safe).
            float4 P[12];
            unroll<12>([&](auto K) {
                constexpr int k = decltype(K)::value;
                P[k] = p4[k];
            });
            float am[8];
            unroll<8>([&](auto K) { am[decltype(K)::value] = -INFINITY; });
            unroll<kT>([&](auto I) {
                constexpr int i = decltype(I)::value;
                am[i % 8] = fmaxf(am[i % 8], Tc[i] + getc<i % 4>(P[i / 4]));
            });
            const float M = fmaxf(fmaxf(fmaxf(am[0], am[4]), fmaxf(am[1], am[5])),
                                  fmaxf(fmaxf(am[2], am[6]), fmaxf(am[3], am[7])));

            // lane i publishes exp(part_i - e_i - M_i)
            const float ea = __expf(pe - M);
            ea_sh[lane] = ea;
            __syncthreads();  // B1: ea visible; pass-1 reads of p_sh done

            // pass 2: S_j = sum_i exp(T[i,j]) * ea_i  (FMA dot product)
            float4 Q[12];
            unroll<12>([&](auto K) {
                constexpr int k = decltype(K)::value;
                Q[k] = q4[k];
            });
            float as[8];
            unroll<8>([&](auto K) { as[decltype(K)::value] = 0.f; });
            unroll<kT>([&](auto I) {
                constexpr int i = decltype(I)::value;
                as[i % 8] = fmaf(Ec[i], getc<i % 4>(Q[i / 4]), as[i % 8]);
            });
            const float Ssum = ((as[0] + as[4]) + (as[1] + as[5])) +
                               ((as[2] + as[6]) + (as[3] + as[7]));

            // val_j = 2*e_j + M_j + log(S_j); mask true so part <- val
            part = 2.0f * e + M + __logf(Ssum);
            p_sh[lane] = part;
            __syncthreads();  // B2: part visible for next step's pass 1
        }
    }

    // Final transition-only step; only end_value[:, T-1] is stored.
    {
        float4 P[12];
        unroll<12>([&](auto K) {
            constexpr int k = decltype(K)::value;
            P[k] = p4[k];
        });
        float am[8];
        unroll<8>([&](auto K) { am[decltype(K)::value] = -INFINITY; });
        unroll<kT>([&](auto I) {
            constexpr int i = decltype(I)::value;
            am[i % 8] = fmaxf(am[i % 8], Tc[i] + getc<i % 4>(P[i / 4]));
        });
        const float M = fmaxf(fmaxf(fmaxf(am[0], am[4]), fmaxf(am[1], am[5])),
                              fmaxf(fmaxf(am[2], am[6]), fmaxf(am[3], am[7])));
        const float ea = __expf(part - M);   // no emission term in final step
        ea_sh[lane] = ea;
        __syncthreads();

        float4 Q[12];
        unroll<12>([&](auto K) {
            constexpr int k = decltype(K)::value;
            Q[k] = q4[k];
        });
        float as[8];
        unroll<8>([&](auto K) { as[decltype(K)::value] = 0.f; });
        unroll<kT>([&](auto I) {
            constexpr int i = decltype(I)::value;
            as[i % 8] = fmaf(Ec[i], getc<i % 4>(Q[i / 4]), as[i % 8]);
        });
        const float Ssum = ((as[0] + as[4]) + (as[1] + as[5])) +
                           ((as[2] + as[6]) + (as[3] + as[7]));
        const float val = M + __logf(Ssum);
        if (lane == kT - 1) out[1 + b] = val;  // score[b] = end_value[b, -1]
    }
}

// out[0] = sum(score). Single wave; no barriers needed.
__global__ __launch_bounds__(64) void sum_scores(
    const float* __restrict__ sc, float* __restrict__ out)
{
    float s = 0.f;
    for (int i = (int)threadIdx.x; i < kB; i += 64) s += sc[i];
#pragma unroll
    for (int off = 32; off > 0; off >>= 1) s += __shfl_down(s, off);
    if (threadIdx.x == 0) out[0] = s;
}

extern "C" void kernel_launch(void* const* d_in, const int* in_sizes, int n_in,
                              void* d_out, int out_size, void* d_ws, size_t ws_size,
                              hipStream_t stream) {
    const float* feats = (const float*)d_in[0];
    const int*   mask  = (const int*)d_in[1];
    const float* trans = (const float*)d_in[2];
    float*       out   = (float*)d_out;

    crf_fwd<<<dim3(kB), dim3(64), 0, stream>>>(feats, mask, trans, out);
    sum_scores<<<dim3(1), dim3(64), 0, stream>>>(out + 1, out);
}